// Round 12
// baseline (1173.618 us; speedup 1.0000x reference)
//
#include <hip/hip_runtime.h>
#include <cstdint>
#include <cstddef>

// ---------------------------------------------------------------------------
// GATv2 x3 + master pooling, bf16-MFMA, CSR-ordered edge pipeline.
// Round-11 structure; this round: edge_fused_k forced to <=64 VGPR via
// __launch_bounds__(256,8) (8 waves/SIMD), aggregate_k degree loop 8-deep.
// ---------------------------------------------------------------------------

typedef __attribute__((ext_vector_type(8))) short bf16x8;
typedef __attribute__((ext_vector_type(4))) float f32x4;
typedef __attribute__((ext_vector_type(8))) unsigned short u16x8;

static __device__ __forceinline__ ushort f2b(float f) {
  uint32_t u = __float_as_uint(f);
  uint32_t r = (u + 0x7fffu + ((u >> 16) & 1u)) >> 16;  // RNE
  return (ushort)r;
}
static __device__ __forceinline__ float b2f(ushort b) {
  return __uint_as_float(((uint32_t)b) << 16);
}

#define GLOAD_LDS16(gp, lp)                                        \
  __builtin_amdgcn_global_load_lds(                                \
      (const __attribute__((address_space(1))) void*)(gp),         \
      (__attribute__((address_space(3))) void*)(lp), 16, 0, 0)

// ---------------- CSR build ----------------
__global__ __launch_bounds__(256) void hist_k(const int* __restrict__ dst,
                                              int* __restrict__ counts, int E) {
  int e = blockIdx.x * 256 + threadIdx.x;
  if (e < E) atomicAdd(&counts[dst[e]], 1);
}

#define SCAN_CHUNK 1024
__global__ __launch_bounds__(256) void scan_sum_k(const int* __restrict__ counts,
                                                  int* __restrict__ bsum, int N) {
  __shared__ int ws[4];
  const int t = threadIdx.x;
  const int i0 = blockIdx.x * SCAN_CHUNK + t * 4;
  int s = 0;
  if (i0 + 3 < N) {
    int4 v = *(const int4*)(counts + i0);
    s = v.x + v.y + v.z + v.w;
  } else {
    for (int k = 0; k < 4; ++k)
      if (i0 + k < N) s += counts[i0 + k];
  }
  for (int off = 1; off < 64; off <<= 1) s += __shfl_xor(s, off);
  if ((t & 63) == 0) ws[t >> 6] = s;
  __syncthreads();
  if (t == 0) bsum[blockIdx.x] = ws[0] + ws[1] + ws[2] + ws[3];
}

__global__ __launch_bounds__(256) void scan_bsum_k(int* __restrict__ bsum, int G) {
  __shared__ int tmp[256];
  const int t = threadIdx.x;
  const int v = (t < G) ? bsum[t] : 0;
  tmp[t] = v;
  __syncthreads();
  for (int off = 1; off < 256; off <<= 1) {
    int u = (t >= off) ? tmp[t - off] : 0;
    __syncthreads();
    tmp[t] += u;
    __syncthreads();
  }
  if (t < G) bsum[t] = tmp[t] - v;  // exclusive
}

__global__ __launch_bounds__(256) void scan_out_k(const int* __restrict__ counts,
                                                  const int* __restrict__ bsum,
                                                  int* __restrict__ rowptr,
                                                  int* __restrict__ cursor,
                                                  int N, int E) {
  __shared__ int wsum[4];
  const int t = threadIdx.x;
  const int lane = t & 63, w = t >> 6;
  const int i0 = blockIdx.x * SCAN_CHUNK + t * 4;
  int v[4] = {0, 0, 0, 0};
  if (i0 + 3 < N) {
    int4 q = *(const int4*)(counts + i0);
    v[0] = q.x; v[1] = q.y; v[2] = q.z; v[3] = q.w;
  } else {
    for (int k = 0; k < 4; ++k)
      if (i0 + k < N) v[k] = counts[i0 + k];
  }
  const int s = v[0] + v[1] + v[2] + v[3];
  int inc = s;
  for (int off = 1; off < 64; off <<= 1) {
    int u = __shfl_up(inc, off);
    if (lane >= off) inc += u;
  }
  if (lane == 63) wsum[w] = inc;
  __syncthreads();
  int wpre = 0;
  for (int k = 0; k < w; ++k) wpre += wsum[k];
  int run = bsum[blockIdx.x] + wpre + inc - s;  // exclusive prefix
  for (int k = 0; k < 4; ++k) {
    const int i = i0 + k;
    if (i < N) {
      rowptr[i] = run;
      cursor[i] = run;
      run += v[k];
    }
  }
  if (blockIdx.x == 0 && t == 0) rowptr[N] = E;
}

// csr[p]=e, srcs[p]=src[e], dsts[p]=dst[e]
__global__ __launch_bounds__(256) void scatter_k(const int* __restrict__ dst,
                                                 const int* __restrict__ src,
                                                 int* __restrict__ cursor,
                                                 int* __restrict__ csr,
                                                 int* __restrict__ srcs,
                                                 int* __restrict__ dsts, int E) {
  int e = blockIdx.x * 256 + threadIdx.x;
  if (e < E) {
    int p = atomicAdd(&cursor[dst[e]], 1);
    csr[p] = e;
    srcs[p] = src[e];
    dsts[p] = dst[e];
  }
}

__global__ __launch_bounds__(256) void master_k(const int* __restrict__ batch,
                                                int* __restrict__ master, int N) {
  int i = blockIdx.x * 256 + threadIdx.x;
  if (i < N) {
    int b = batch[i];
    if (i == N - 1 || batch[i + 1] != b) master[b] = i;
  }
}

// ---------------- conversions ----------------
__global__ __launch_bounds__(256) void cvt_k(const float* __restrict__ in,
                                             ushort* __restrict__ out, int n4) {
  int i = blockIdx.x * 256 + threadIdx.x;
  if (i < n4) {
    float4 v = ((const float4*)in)[i];
    ushort4 o;
    o.x = f2b(v.x); o.y = f2b(v.y); o.z = f2b(v.z); o.w = f2b(v.w);
    ((ushort4*)out)[i] = o;
  }
}

__global__ __launch_bounds__(256) void ebp_cvt_k(const float* __restrict__ ea,
                                                 const int* __restrict__ csr,
                                                 ushort* __restrict__ ebc, int E) {
  const int idx = blockIdx.x * 256 + threadIdx.x;
  const int i = idx >> 4, t = idx & 15;
  if (i < E) {
    float4 v = *(const float4*)(ea + (size_t)csr[i] * 64 + t * 4);
    ushort4 o;
    o.x = f2b(v.x); o.y = f2b(v.y); o.z = f2b(v.z); o.w = f2b(v.w);
    *(ushort4*)(ebc + (size_t)i * 64 + t * 4) = o;
  }
}

// all weight transposes (3 layers) in one launch
__global__ __launch_bounds__(256) void wtall_k(
    const float* __restrict__ w1l, const float* __restrict__ w1r,
    const float* __restrict__ w1e, const float* __restrict__ w2l,
    const float* __restrict__ w2r, const float* __restrict__ w2e,
    const float* __restrict__ w3l, const float* __restrict__ w3r,
    const float* __restrict__ w3e, ushort* __restrict__ wt0,
    ushort* __restrict__ wt1, ushort* __restrict__ wt2,
    ushort* __restrict__ wet, int IN) {
  const int y = blockIdx.y;
  const int i = blockIdx.x * 256 + threadIdx.x;
  if (y < 3) {
    const int K = (y == 0) ? IN : 128;
    ushort* out = (y == 0) ? wt0 : ((y == 1) ? wt1 : wt2);
    const float* Wl = (y == 0) ? w1l : ((y == 1) ? w2l : w3l);
    const float* Wr = (y == 0) ? w1r : ((y == 1) ? w2r : w3r);
    if (i < 512 * K) {
      const int n = i / K, k = i - n * K;
      const float* W = (n < 256) ? Wl : Wr;
      out[(size_t)n * K + k] = f2b(W[(size_t)k * 256 + (n & 255)]);
    }
  } else {
    if (i < 3 * 256 * 64) {
      const int l = i / (256 * 64);
      const int r = i - l * 256 * 64;
      const int n = r / 64, k = r - n * 64;
      const float* W = (l == 0) ? w1e : ((l == 1) ? w2e : w3e);
      wet[(size_t)l * 16384 + (size_t)n * 64 + k] = f2b(W[(size_t)k * 256 + n]);
    }
  }
}

// ---------------- bf16 MFMA GEMM (node features) ----------------
// C[M,512] = A[M,K] @ Bt[512,K]^T. 128x256 tile, BK=64, 8 waves (2x4).
__global__ __launch_bounds__(512) void gemm_bf16(const ushort* __restrict__ A,
                                                 const ushort* __restrict__ Bt,
                                                 ushort* __restrict__ C,
                                                 int M, int N, int K) {
  __shared__ ushort As[128 * 64];  // 16KB
  __shared__ ushort Bs[256 * 64];  // 32KB
  const int tid = threadIdx.x;
  const int lane = tid & 63;
  const int wave = tid >> 6;        // 0..7
  const int bm = blockIdx.x * 128;
  const int bn = blockIdx.y * 256;
  const int wm = (wave >> 2) * 64;  // 0,64
  const int wn = (wave & 3) * 64;   // 0..192
  const int l15 = lane & 15;
  const int t_hi = lane >> 4;

  f32x4 acc[4][4] = {};

  const int wb = tid & ~63;  // wave-uniform base within 512
  int arow[2], aks[2];
#pragma unroll
  for (int i = 0; i < 2; ++i) {
    const int j = i * 512 + wb + lane;
    arow[i] = j >> 3;                     // 0..127
    aks[i] = (j & 7) ^ (arow[i] & 7);
  }
  int brow[4], bks[4];
#pragma unroll
  for (int i = 0; i < 4; ++i) {
    const int j = i * 512 + wb + lane;
    brow[i] = j >> 3;                     // 0..255
    bks[i] = (j & 7) ^ (brow[i] & 7);
  }

  for (int k0 = 0; k0 < K; k0 += 64) {
#pragma unroll
    for (int i = 0; i < 2; ++i) {
      const int ar = min(bm + arow[i], M - 1);  // clamp tail (masked on store)
      GLOAD_LDS16(A + (size_t)ar * K + k0 + aks[i] * 8,
                  As + (size_t)(i * 512 + wb) * 8);
    }
#pragma unroll
    for (int i = 0; i < 4; ++i) {
      GLOAD_LDS16(Bt + (size_t)(bn + brow[i]) * K + k0 + bks[i] * 8,
                  Bs + (size_t)(i * 512 + wb) * 8);
    }
    __syncthreads();
#pragma unroll
    for (int ks = 0; ks < 2; ++ks) {
      bf16x8 af[4], bfr[4];
#pragma unroll
      for (int f = 0; f < 4; ++f) {
        const int q = (ks * 4 + t_hi) ^ (lane & 7);
        af[f]  = *(const bf16x8*)&As[(wm + f * 16 + l15) * 64 + q * 8];
        bfr[f] = *(const bf16x8*)&Bs[(wn + f * 16 + l15) * 64 + q * 8];
      }
#pragma unroll
      for (int fm = 0; fm < 4; ++fm)
#pragma unroll
        for (int fn = 0; fn < 4; ++fn)
          acc[fm][fn] = __builtin_amdgcn_mfma_f32_16x16x32_bf16(
              af[fm], bfr[fn], acc[fm][fn], 0, 0, 0);
    }
    __syncthreads();
  }
#pragma unroll
  for (int fm = 0; fm < 4; ++fm) {
    const int r0 = bm + wm + fm * 16 + t_hi * 4;
#pragma unroll
    for (int j = 0; j < 4; ++j) {
      const int gr = r0 + j;
      if (gr < M) {
#pragma unroll
        for (int fn = 0; fn < 4; ++fn) {
          const int gc = bn + wn + fn * 16 + l15;
          C[(size_t)gr * N + gc] = f2b(acc[fm][fn][j]);
        }
      }
    }
  }
}

// ---------------- fused edge projection + logits (CSR order) ----------------
// grid ceil(E/64), 256 threads (4 waves), 64 edges per block. Wave w covers
// c-slice wm = w*64 over all 64 slots. __launch_bounds__(256,8) caps VGPR at
// 64 (proven feasible by the identical-shape 512-thread variant) -> 8
// waves/SIMD for gather-latency hiding.
__global__ __launch_bounds__(256, 8) void edge_fused_k(
    const ushort* __restrict__ ebc,  // [E][64] CSR-ordered
    const ushort* __restrict__ wet,  // [256][64] (this layer)
    const ushort* __restrict__ xlr,  // [N][512]
    const float* __restrict__ att,   // [256]
    const int* __restrict__ srcs, const int* __restrict__ dsts,
    float* __restrict__ payload_f, int E) {
  __shared__ ushort Bs[64 * 64];      // 8KB
  __shared__ int sSrc[64], sDst[64];
  __shared__ float red[2][2][64];     // [head][c-group][slot]

  const int tid = threadIdx.x;
  const int lane = tid & 63;
  const int wave = tid >> 6;           // 0..3
  const int bm = blockIdx.x * 64;      // CSR slot base
  const int wm = wave * 64;            // c offset 0..255
  const int l15 = lane & 15;
  const int t_hi = lane >> 4;

  if (tid < 64) {
    const int i = min(bm + tid, E - 1);
    sSrc[tid] = srcs[i];
    sDst[tid] = dsts[i];
  }

  // stage ebc tile (64 rows x K=64): swizzle-on-source, linear LDS dest
  const int wb = tid & ~63;
#pragma unroll
  for (int i = 0; i < 2; ++i) {
    const int j = i * 256 + wb + lane;
    const int jrow = j >> 3;
    const int jks = (j & 7) ^ (jrow & 7);
    const int er = min(bm + jrow, E - 1);
    GLOAD_LDS16(ebc + (size_t)er * 64 + jks * 8,
                Bs + (size_t)(i * 256 + wb) * 8);
  }
  __syncthreads();

  f32x4 acc[4][4] = {};
#pragma unroll
  for (int ks = 0; ks < 2; ++ks) {
    bf16x8 af[4], bfr[4];
#pragma unroll
    for (int f = 0; f < 4; ++f) {
      const int q = (ks * 4 + t_hi) ^ (lane & 7);
      bfr[f] = *(const bf16x8*)&Bs[(f * 16 + l15) * 64 + q * 8];
      af[f] = *(const bf16x8*)&wet[(size_t)(wm + f * 16 + l15) * 64 +
                                   (ks * 4 + t_hi) * 8];
    }
#pragma unroll
    for (int fm = 0; fm < 4; ++fm)
#pragma unroll
      for (int fn = 0; fn < 4; ++fn)
        acc[fm][fn] = __builtin_amdgcn_mfma_f32_16x16x32_bf16(
            af[fm], bfr[fn], acc[fm][fn], 0, 0, 0);
  }

  // epilogue: per lane, 4 slot-groups (fn), 16 c-values each (fm x j)
  float p[4];
#pragma unroll
  for (int fn = 0; fn < 4; ++fn) {
    const int el = fn * 16 + l15;
    const int s = sSrc[el];
    const int d = sDst[el];
    const ushort* xlp = xlr + (((size_t)s) << 9) + wm + t_hi * 4;
    const ushort* xrp = xlr + (((size_t)d) << 9) + 256 + wm + t_hi * 4;
    float ap = 0.f;
#pragma unroll
    for (int fm = 0; fm < 4; ++fm) {
      const ushort4 xa = *(const ushort4*)(xlp + fm * 16);
      const ushort4 xc = *(const ushort4*)(xrp + fm * 16);
      const float4 at4 = *(const float4*)(att + wm + fm * 16 + t_hi * 4);
      float q0 = acc[fm][fn][0] + b2f(xa.x) + b2f(xc.x);
      float q1 = acc[fm][fn][1] + b2f(xa.y) + b2f(xc.y);
      float q2 = acc[fm][fn][2] + b2f(xa.z) + b2f(xc.z);
      float q3 = acc[fm][fn][3] + b2f(xa.w) + b2f(xc.w);
      q0 = q0 > 0.f ? q0 : 0.2f * q0;
      q1 = q1 > 0.f ? q1 : 0.2f * q1;
      q2 = q2 > 0.f ? q2 : 0.2f * q2;
      q3 = q3 > 0.f ? q3 : 0.2f * q3;
      ap += q0 * at4.x + q1 * at4.y + q2 * at4.z + q3 * at4.w;
    }
    p[fn] = ap;
  }
#pragma unroll
  for (int fn = 0; fn < 4; ++fn) {
    p[fn] += __shfl_xor(p[fn], 16);
    p[fn] += __shfl_xor(p[fn], 32);
  }
  if (lane < 16) {
    const int h = wave >> 1;
    const int g = wave & 1;
#pragma unroll
    for (int fn = 0; fn < 4; ++fn)
      red[h][g][fn * 16 + lane] = p[fn];
  }
  __syncthreads();
  if (tid < 128) {
    const int slot = tid & 63, h = tid >> 6;
    const int i = bm + slot;
    if (i < E) payload_f[2 * (size_t)i + h] = red[h][0][slot] + red[h][1][slot];
  }
}

// ---------------- per-node segment softmax + aggregation ----------------
// one wave per node; lanes 0-31 even CSR slots, 32-63 odd; within a 32-group
// lanes 0-15 = head0 weights, 16-31 = head1. Degree loop batched 8-deep
// (8 independent 16B gathers in flight per lane).
__global__ __launch_bounds__(256) void aggregate_k(
    const ushort* __restrict__ xlr, const float2* __restrict__ payload,
    const int* __restrict__ rowptr, const int* __restrict__ srcs,
    const float* __restrict__ bias, ushort* __restrict__ hb,
    float* __restrict__ hf, int N, int relu) {
  const int n = blockIdx.x * 4 + (threadIdx.x >> 6);
  if (n >= N) return;
  const int lane = threadIdx.x & 63;
  const int half = lane >> 5;
  const int sl = lane & 31;
  const int hsel = sl >> 4;
  const int beg = rowptr[n], end = rowptr[n + 1];
  if (beg >= end) {
    if (lane < 16) {
      const int c0 = sl * 8;
      u16x8 ob;
      float o[8];
#pragma unroll
      for (int t = 0; t < 8; ++t) {
        float v = bias[c0 + t];
        if (relu) v = fmaxf(v, 0.f);
        o[t] = v;
        ob[t] = f2b(v);
      }
      *(u16x8*)(hb + (size_t)n * 128 + c0) = ob;
      if (hf) {
        *(float4*)(hf + (size_t)n * 128 + c0) = make_float4(o[0], o[1], o[2], o[3]);
        *(float4*)(hf + (size_t)n * 128 + c0 + 4) = make_float4(o[4], o[5], o[6], o[7]);
      }
    }
    return;
  }

  float m0 = -1e30f, m1 = -1e30f;
  for (int i = beg + half; i < end; i += 2) {
    const float2 lg = payload[i];
    m0 = fmaxf(m0, lg.x);
    m1 = fmaxf(m1, lg.y);
  }
  m0 = fmaxf(m0, __shfl_xor(m0, 32));
  m1 = fmaxf(m1, __shfl_xor(m1, 32));

  float s0 = 0.f, s1 = 0.f;
  float acc[8] = {};
  for (int base = beg + half; base < end; base += 16) {
    float2 lg[8];
    int sidx[8];
#pragma unroll
    for (int k = 0; k < 8; ++k) {
      const int i = min(base + 2 * k, end - 1);
      lg[k] = payload[i];
      sidx[k] = srcs[i];
    }
    u16x8 v[8];
#pragma unroll
    for (int k = 0; k < 8; ++k)
      v[k] = *(const u16x8*)(xlr + (((size_t)sidx[k]) << 9) + sl * 8);
    float wv[8];
#pragma unroll
    for (int k = 0; k < 8; ++k) {
      const bool ok = (base + 2 * k) < end;
      const float w0 = ok ? __expf(lg[k].x - m0) : 0.f;
      const float w1 = ok ? __expf(lg[k].y - m1) : 0.f;
      s0 += w0; s1 += w1;
      wv[k] = hsel ? w1 : w0;
    }
#pragma unroll
    for (int k = 0; k < 8; ++k)
#pragma unroll
      for (int t = 0; t < 8; ++t) acc[t] += wv[k] * b2f((ushort)v[k][t]);
  }
  s0 += __shfl_xor(s0, 32);
  s1 += __shfl_xor(s1, 32);
#pragma unroll
  for (int t = 0; t < 8; ++t) acc[t] += __shfl_xor(acc[t], 32);

  const float i0 = 1.f / (s0 + 1e-16f);
  const float i1 = 1.f / (s1 + 1e-16f);
  const float myinv = hsel ? i1 : i0;
  const int c0 = (sl & 15) * 8;
  float o[8];
#pragma unroll
  for (int t = 0; t < 8; ++t) {
    const float mine = acc[t] * myinv;
    const float other = __shfl_xor(mine, 16);
    float v = 0.5f * (mine + other) + bias[c0 + t];
    if (relu) v = fmaxf(v, 0.f);
    o[t] = v;
  }
  if (lane < 16) {
    u16x8 ob;
#pragma unroll
    for (int t = 0; t < 8; ++t) ob[t] = f2b(o[t]);
    *(u16x8*)(hb + (size_t)n * 128 + c0) = ob;
    if (hf) {
      *(float4*)(hf + (size_t)n * 128 + c0) = make_float4(o[0], o[1], o[2], o[3]);
      *(float4*)(hf + (size_t)n * 128 + c0 + 4) = make_float4(o[4], o[5], o[6], o[7]);
    }
  }
}

__global__ __launch_bounds__(128) void gather_k(const float* __restrict__ h,
                                                const int* __restrict__ master,
                                                float* __restrict__ out) {
  out[(size_t)blockIdx.x * 128 + threadIdx.x] =
      h[(size_t)master[blockIdx.x] * 128 + threadIdx.x];
}

// ---------------------------------------------------------------------------
extern "C" void kernel_launch(void* const* d_in, const int* in_sizes, int n_in,
                              void* d_out, int out_size, void* d_ws, size_t ws_size,
                              hipStream_t stream) {
  const float* x     = (const float*)d_in[0];
  const int*   ei    = (const int*)d_in[1];
  const float* eattr = (const float*)d_in[2];
  const int*   batch = (const int*)d_in[3];

  const int N  = in_sizes[3];
  const int E  = in_sizes[1] / 2;
  const int IN = in_sizes[0] / N;
  const int B  = out_size / 128;

  const int* src  = ei;
  const int* dstp = ei + E;

  char* p = (char*)d_ws;
  auto carve = [&](size_t bytes) {
    void* r = (void*)p;
    p += (bytes + 255) & ~(size_t)255;
    return r;
  };
  ushort* xb     = (ushort*)carve((size_t)N * 512 * 2);  // bf16(x); dead after L1 GEMM
  ushort* ebc    = (ushort*)carve((size_t)E * 64 * 2);   // bf16 edge_attr, CSR order
  ushort* xlr    = (ushort*)carve((size_t)N * 512 * 2);  // [xl | xr] bf16
  ushort* h1b    = (ushort*)carve((size_t)N * 128 * 2);
  ushort* h2b    = (ushort*)carve((size_t)N * 128 * 2);
  ushort* wt0    = (ushort*)carve((size_t)512 * 512 * 2);
  ushort* wt1    = (ushort*)carve((size_t)512 * 128 * 2);
  ushort* wt2    = (ushort*)carve((size_t)512 * 128 * 2);
  ushort* wet    = (ushort*)carve((size_t)3 * 256 * 64 * 2);
  float2* payload= (float2*)carve((size_t)E * 8);        // CSR-ordered logits
  int* counts    = (int*)carve(((size_t)N + B) * 4);
  int* master    = counts + N;
  int* rowptr    = (int*)carve(((size_t)N + 1) * 4);
  int* cursor    = (int*)carve((size_t)N * 4);
  int* csr       = (int*)carve((size_t)E * 4);
  int* srcs      = (int*)carve((size_t)E * 4);           // src in CSR order
  int* dsts      = (int*)carve((size_t)E * 4);           // dst in CSR order
  int* bsum      = (int*)carve(256 * 4);
  float* hf      = (float*)xb;                            // f32 h3 aliases dead xb
  (void)ws_size; (void)n_in;

  const int G = (N + SCAN_CHUNK - 1) / SCAN_CHUNK;

  // setup (once; reused by all 3 layers)
  hipMemsetAsync(counts, 0, ((size_t)N + B) * 4, stream);
  hist_k<<<(E + 255) / 256, 256, 0, stream>>>(dstp, counts, E);
  scan_sum_k<<<G, 256, 0, stream>>>(counts, bsum, N);
  scan_bsum_k<<<1, 256, 0, stream>>>(bsum, G);
  scan_out_k<<<G, 256, 0, stream>>>(counts, bsum, rowptr, cursor, N, E);
  scatter_k<<<(E + 255) / 256, 256, 0, stream>>>(dstp, src, cursor, csr, srcs,
                                                 dsts, E);
  master_k<<<(N + 255) / 256, 256, 0, stream>>>(batch, master, N);
  ebp_cvt_k<<<(E * 16 + 255) / 256, 256, 0, stream>>>(eattr, csr, ebc, E);

  {
    int n4 = N * IN / 4;
    cvt_k<<<(n4 + 255) / 256, 256, 0, stream>>>(x, xb, n4);
  }

  wtall_k<<<dim3((512 * IN + 255) / 256, 4), 256, 0, stream>>>(
      (const float*)d_in[4], (const float*)d_in[5], (const float*)d_in[6],
      (const float*)d_in[9], (const float*)d_in[10], (const float*)d_in[11],
      (const float*)d_in[14], (const float*)d_in[15], (const float*)d_in[16],
      wt0, wt1, wt2, wet, IN);

  const int edge_grid = (E + 63) / 64;
  const int agg_grid = (N + 3) / 4;
  ushort* wts[3] = {wt0, wt1, wt2};
  for (int l = 0; l < 3; ++l) {
    const float* att = (const float*)d_in[4 + 5 * l + 3];
    const float* bv  = (const float*)d_in[4 + 5 * l + 4];
    const int K = (l == 0) ? IN : 128;

    const ushort* Ab = (l == 0) ? xb : ((l == 1) ? h1b : h2b);
    gemm_bf16<<<dim3((N + 127) / 128, 2), 512, 0, stream>>>(Ab, wts[l], xlr,
                                                            N, 512, K);

    edge_fused_k<<<edge_grid, 256, 0, stream>>>(ebc, wet + (size_t)l * 16384,
                                                xlr, att, srcs, dsts,
                                                (float*)payload, E);

    ushort* hb = (l == 0) ? h1b : ((l == 1) ? h2b : h1b);
    aggregate_k<<<agg_grid, 256, 0, stream>>>(xlr, payload, rowptr, srcs, bv,
                                              hb, (l == 2) ? hf : nullptr, N,
                                              l < 2 ? 1 : 0);
  }

  gather_k<<<B, 128, 0, stream>>>(hf, master, (float*)d_out);
}

// Round 13
// 655.360 us; speedup vs baseline: 1.7908x; 1.7908x over previous
//
#include <hip/hip_runtime.h>
#include <cstdint>
#include <cstddef>

// ---------------------------------------------------------------------------
// GATv2 x3 + master pooling, bf16-MFMA, CSR-ordered edge pipeline.
// Round-11 structure; this round: edge_fused_k hoists ALL 32 epilogue
// gathers into registers BEFORE the MFMA loop (in-wave MLP: 32 outstanding
// loads whose latency hides under the matrix work). aggregate 8-deep kept.
// ---------------------------------------------------------------------------

typedef __attribute__((ext_vector_type(8))) short bf16x8;
typedef __attribute__((ext_vector_type(4))) float f32x4;
typedef __attribute__((ext_vector_type(8))) unsigned short u16x8;

static __device__ __forceinline__ ushort f2b(float f) {
  uint32_t u = __float_as_uint(f);
  uint32_t r = (u + 0x7fffu + ((u >> 16) & 1u)) >> 16;  // RNE
  return (ushort)r;
}
static __device__ __forceinline__ float b2f(ushort b) {
  return __uint_as_float(((uint32_t)b) << 16);
}

#define GLOAD_LDS16(gp, lp)                                        \
  __builtin_amdgcn_global_load_lds(                                \
      (const __attribute__((address_space(1))) void*)(gp),         \
      (__attribute__((address_space(3))) void*)(lp), 16, 0, 0)

// ---------------- CSR build ----------------
__global__ __launch_bounds__(256) void hist_k(const int* __restrict__ dst,
                                              int* __restrict__ counts, int E) {
  int e = blockIdx.x * 256 + threadIdx.x;
  if (e < E) atomicAdd(&counts[dst[e]], 1);
}

#define SCAN_CHUNK 1024
__global__ __launch_bounds__(256) void scan_sum_k(const int* __restrict__ counts,
                                                  int* __restrict__ bsum, int N) {
  __shared__ int ws[4];
  const int t = threadIdx.x;
  const int i0 = blockIdx.x * SCAN_CHUNK + t * 4;
  int s = 0;
  if (i0 + 3 < N) {
    int4 v = *(const int4*)(counts + i0);
    s = v.x + v.y + v.z + v.w;
  } else {
    for (int k = 0; k < 4; ++k)
      if (i0 + k < N) s += counts[i0 + k];
  }
  for (int off = 1; off < 64; off <<= 1) s += __shfl_xor(s, off);
  if ((t & 63) == 0) ws[t >> 6] = s;
  __syncthreads();
  if (t == 0) bsum[blockIdx.x] = ws[0] + ws[1] + ws[2] + ws[3];
}

__global__ __launch_bounds__(256) void scan_bsum_k(int* __restrict__ bsum, int G) {
  __shared__ int tmp[256];
  const int t = threadIdx.x;
  const int v = (t < G) ? bsum[t] : 0;
  tmp[t] = v;
  __syncthreads();
  for (int off = 1; off < 256; off <<= 1) {
    int u = (t >= off) ? tmp[t - off] : 0;
    __syncthreads();
    tmp[t] += u;
    __syncthreads();
  }
  if (t < G) bsum[t] = tmp[t] - v;  // exclusive
}

__global__ __launch_bounds__(256) void scan_out_k(const int* __restrict__ counts,
                                                  const int* __restrict__ bsum,
                                                  int* __restrict__ rowptr,
                                                  int* __restrict__ cursor,
                                                  int N, int E) {
  __shared__ int wsum[4];
  const int t = threadIdx.x;
  const int lane = t & 63, w = t >> 6;
  const int i0 = blockIdx.x * SCAN_CHUNK + t * 4;
  int v[4] = {0, 0, 0, 0};
  if (i0 + 3 < N) {
    int4 q = *(const int4*)(counts + i0);
    v[0] = q.x; v[1] = q.y; v[2] = q.z; v[3] = q.w;
  } else {
    for (int k = 0; k < 4; ++k)
      if (i0 + k < N) v[k] = counts[i0 + k];
  }
  const int s = v[0] + v[1] + v[2] + v[3];
  int inc = s;
  for (int off = 1; off < 64; off <<= 1) {
    int u = __shfl_up(inc, off);
    if (lane >= off) inc += u;
  }
  if (lane == 63) wsum[w] = inc;
  __syncthreads();
  int wpre = 0;
  for (int k = 0; k < w; ++k) wpre += wsum[k];
  int run = bsum[blockIdx.x] + wpre + inc - s;  // exclusive prefix
  for (int k = 0; k < 4; ++k) {
    const int i = i0 + k;
    if (i < N) {
      rowptr[i] = run;
      cursor[i] = run;
      run += v[k];
    }
  }
  if (blockIdx.x == 0 && t == 0) rowptr[N] = E;
}

// csr[p]=e, srcs[p]=src[e], dsts[p]=dst[e]
__global__ __launch_bounds__(256) void scatter_k(const int* __restrict__ dst,
                                                 const int* __restrict__ src,
                                                 int* __restrict__ cursor,
                                                 int* __restrict__ csr,
                                                 int* __restrict__ srcs,
                                                 int* __restrict__ dsts, int E) {
  int e = blockIdx.x * 256 + threadIdx.x;
  if (e < E) {
    int p = atomicAdd(&cursor[dst[e]], 1);
    csr[p] = e;
    srcs[p] = src[e];
    dsts[p] = dst[e];
  }
}

__global__ __launch_bounds__(256) void master_k(const int* __restrict__ batch,
                                                int* __restrict__ master, int N) {
  int i = blockIdx.x * 256 + threadIdx.x;
  if (i < N) {
    int b = batch[i];
    if (i == N - 1 || batch[i + 1] != b) master[b] = i;
  }
}

// ---------------- conversions ----------------
__global__ __launch_bounds__(256) void cvt_k(const float* __restrict__ in,
                                             ushort* __restrict__ out, int n4) {
  int i = blockIdx.x * 256 + threadIdx.x;
  if (i < n4) {
    float4 v = ((const float4*)in)[i];
    ushort4 o;
    o.x = f2b(v.x); o.y = f2b(v.y); o.z = f2b(v.z); o.w = f2b(v.w);
    ((ushort4*)out)[i] = o;
  }
}

__global__ __launch_bounds__(256) void ebp_cvt_k(const float* __restrict__ ea,
                                                 const int* __restrict__ csr,
                                                 ushort* __restrict__ ebc, int E) {
  const int idx = blockIdx.x * 256 + threadIdx.x;
  const int i = idx >> 4, t = idx & 15;
  if (i < E) {
    float4 v = *(const float4*)(ea + (size_t)csr[i] * 64 + t * 4);
    ushort4 o;
    o.x = f2b(v.x); o.y = f2b(v.y); o.z = f2b(v.z); o.w = f2b(v.w);
    *(ushort4*)(ebc + (size_t)i * 64 + t * 4) = o;
  }
}

// all weight transposes (3 layers) in one launch
__global__ __launch_bounds__(256) void wtall_k(
    const float* __restrict__ w1l, const float* __restrict__ w1r,
    const float* __restrict__ w1e, const float* __restrict__ w2l,
    const float* __restrict__ w2r, const float* __restrict__ w2e,
    const float* __restrict__ w3l, const float* __restrict__ w3r,
    const float* __restrict__ w3e, ushort* __restrict__ wt0,
    ushort* __restrict__ wt1, ushort* __restrict__ wt2,
    ushort* __restrict__ wet, int IN) {
  const int y = blockIdx.y;
  const int i = blockIdx.x * 256 + threadIdx.x;
  if (y < 3) {
    const int K = (y == 0) ? IN : 128;
    ushort* out = (y == 0) ? wt0 : ((y == 1) ? wt1 : wt2);
    const float* Wl = (y == 0) ? w1l : ((y == 1) ? w2l : w3l);
    const float* Wr = (y == 0) ? w1r : ((y == 1) ? w2r : w3r);
    if (i < 512 * K) {
      const int n = i / K, k = i - n * K;
      const float* W = (n < 256) ? Wl : Wr;
      out[(size_t)n * K + k] = f2b(W[(size_t)k * 256 + (n & 255)]);
    }
  } else {
    if (i < 3 * 256 * 64) {
      const int l = i / (256 * 64);
      const int r = i - l * 256 * 64;
      const int n = r / 64, k = r - n * 64;
      const float* W = (l == 0) ? w1e : ((l == 1) ? w2e : w3e);
      wet[(size_t)l * 16384 + (size_t)n * 64 + k] = f2b(W[(size_t)k * 256 + n]);
    }
  }
}

// ---------------- bf16 MFMA GEMM (node features) ----------------
// C[M,512] = A[M,K] @ Bt[512,K]^T. 128x256 tile, BK=64, 8 waves (2x4).
__global__ __launch_bounds__(512) void gemm_bf16(const ushort* __restrict__ A,
                                                 const ushort* __restrict__ Bt,
                                                 ushort* __restrict__ C,
                                                 int M, int N, int K) {
  __shared__ ushort As[128 * 64];  // 16KB
  __shared__ ushort Bs[256 * 64];  // 32KB
  const int tid = threadIdx.x;
  const int lane = tid & 63;
  const int wave = tid >> 6;        // 0..7
  const int bm = blockIdx.x * 128;
  const int bn = blockIdx.y * 256;
  const int wm = (wave >> 2) * 64;  // 0,64
  const int wn = (wave & 3) * 64;   // 0..192
  const int l15 = lane & 15;
  const int t_hi = lane >> 4;

  f32x4 acc[4][4] = {};

  const int wb = tid & ~63;  // wave-uniform base within 512
  int arow[2], aks[2];
#pragma unroll
  for (int i = 0; i < 2; ++i) {
    const int j = i * 512 + wb + lane;
    arow[i] = j >> 3;                     // 0..127
    aks[i] = (j & 7) ^ (arow[i] & 7);
  }
  int brow[4], bks[4];
#pragma unroll
  for (int i = 0; i < 4; ++i) {
    const int j = i * 512 + wb + lane;
    brow[i] = j >> 3;                     // 0..255
    bks[i] = (j & 7) ^ (brow[i] & 7);
  }

  for (int k0 = 0; k0 < K; k0 += 64) {
#pragma unroll
    for (int i = 0; i < 2; ++i) {
      const int ar = min(bm + arow[i], M - 1);  // clamp tail (masked on store)
      GLOAD_LDS16(A + (size_t)ar * K + k0 + aks[i] * 8,
                  As + (size_t)(i * 512 + wb) * 8);
    }
#pragma unroll
    for (int i = 0; i < 4; ++i) {
      GLOAD_LDS16(Bt + (size_t)(bn + brow[i]) * K + k0 + bks[i] * 8,
                  Bs + (size_t)(i * 512 + wb) * 8);
    }
    __syncthreads();
#pragma unroll
    for (int ks = 0; ks < 2; ++ks) {
      bf16x8 af[4], bfr[4];
#pragma unroll
      for (int f = 0; f < 4; ++f) {
        const int q = (ks * 4 + t_hi) ^ (lane & 7);
        af[f]  = *(const bf16x8*)&As[(wm + f * 16 + l15) * 64 + q * 8];
        bfr[f] = *(const bf16x8*)&Bs[(wn + f * 16 + l15) * 64 + q * 8];
      }
#pragma unroll
      for (int fm = 0; fm < 4; ++fm)
#pragma unroll
        for (int fn = 0; fn < 4; ++fn)
          acc[fm][fn] = __builtin_amdgcn_mfma_f32_16x16x32_bf16(
              af[fm], bfr[fn], acc[fm][fn], 0, 0, 0);
    }
    __syncthreads();
  }
#pragma unroll
  for (int fm = 0; fm < 4; ++fm) {
    const int r0 = bm + wm + fm * 16 + t_hi * 4;
#pragma unroll
    for (int j = 0; j < 4; ++j) {
      const int gr = r0 + j;
      if (gr < M) {
#pragma unroll
        for (int fn = 0; fn < 4; ++fn) {
          const int gc = bn + wn + fn * 16 + l15;
          C[(size_t)gr * N + gc] = f2b(acc[fm][fn][j]);
        }
      }
    }
  }
}

// ---------------- fused edge projection + logits (CSR order) ----------------
// grid ceil(E/64), 256 threads (4 waves), 64 edges per block. Wave w covers
// c-slice wm = w*64 over all 64 slots. ALL 32 xl/xr gathers are issued into
// registers BEFORE the MFMA loop: they depend only on sSrc/sDst, so their
// ~500cy latency hides under the matrix work and the wave keeps 32 loads in
// flight (vs ~1 when interleaved per-fn after the MFMA).
__global__ __launch_bounds__(256) void edge_fused_k(
    const ushort* __restrict__ ebc,  // [E][64] CSR-ordered
    const ushort* __restrict__ wet,  // [256][64] (this layer)
    const ushort* __restrict__ xlr,  // [N][512]
    const float* __restrict__ att,   // [256]
    const int* __restrict__ srcs, const int* __restrict__ dsts,
    float* __restrict__ payload_f, int E) {
  __shared__ ushort Bs[64 * 64];      // 8KB
  __shared__ int sSrc[64], sDst[64];
  __shared__ float red[2][2][64];     // [head][c-group][slot]

  const int tid = threadIdx.x;
  const int lane = tid & 63;
  const int wave = tid >> 6;           // 0..3
  const int bm = blockIdx.x * 64;      // CSR slot base
  const int wm = wave * 64;            // c offset 0..255
  const int l15 = lane & 15;
  const int t_hi = lane >> 4;

  if (tid < 64) {
    const int i = min(bm + tid, E - 1);
    sSrc[tid] = srcs[i];
    sDst[tid] = dsts[i];
  }

  // stage ebc tile (64 rows x K=64): swizzle-on-source, linear LDS dest
  const int wb = tid & ~63;
#pragma unroll
  for (int i = 0; i < 2; ++i) {
    const int j = i * 256 + wb + lane;
    const int jrow = j >> 3;
    const int jks = (j & 7) ^ (jrow & 7);
    const int er = min(bm + jrow, E - 1);
    GLOAD_LDS16(ebc + (size_t)er * 64 + jks * 8,
                Bs + (size_t)(i * 256 + wb) * 8);
  }
  __syncthreads();

  // ---- hoisted gathers: all 32 loads in flight before the MFMA ----
  ushort4 xa[4][4], xc[4][4];
#pragma unroll
  for (int fn = 0; fn < 4; ++fn) {
    const int el = fn * 16 + l15;
    const ushort* xlp = xlr + (((size_t)sSrc[el]) << 9) + wm + t_hi * 4;
    const ushort* xrp = xlr + (((size_t)sDst[el]) << 9) + 256 + wm + t_hi * 4;
#pragma unroll
    for (int fm = 0; fm < 4; ++fm) {
      xa[fn][fm] = *(const ushort4*)(xlp + fm * 16);
      xc[fn][fm] = *(const ushort4*)(xrp + fm * 16);
    }
  }

  f32x4 acc[4][4] = {};
#pragma unroll
  for (int ks = 0; ks < 2; ++ks) {
    bf16x8 af[4], bfr[4];
#pragma unroll
    for (int f = 0; f < 4; ++f) {
      const int q = (ks * 4 + t_hi) ^ (lane & 7);
      bfr[f] = *(const bf16x8*)&Bs[(f * 16 + l15) * 64 + q * 8];
      af[f] = *(const bf16x8*)&wet[(size_t)(wm + f * 16 + l15) * 64 +
                                   (ks * 4 + t_hi) * 8];
    }
#pragma unroll
    for (int fm = 0; fm < 4; ++fm)
#pragma unroll
      for (int fn = 0; fn < 4; ++fn)
        acc[fm][fn] = __builtin_amdgcn_mfma_f32_16x16x32_bf16(
            af[fm], bfr[fn], acc[fm][fn], 0, 0, 0);
  }

  // epilogue: consume hoisted gathers
  float p[4];
#pragma unroll
  for (int fn = 0; fn < 4; ++fn) {
    float ap = 0.f;
#pragma unroll
    for (int fm = 0; fm < 4; ++fm) {
      const float4 at4 = *(const float4*)(att + wm + fm * 16 + t_hi * 4);
      float q0 = acc[fm][fn][0] + b2f(xa[fn][fm].x) + b2f(xc[fn][fm].x);
      float q1 = acc[fm][fn][1] + b2f(xa[fn][fm].y) + b2f(xc[fn][fm].y);
      float q2 = acc[fm][fn][2] + b2f(xa[fn][fm].z) + b2f(xc[fn][fm].z);
      float q3 = acc[fm][fn][3] + b2f(xa[fn][fm].w) + b2f(xc[fn][fm].w);
      q0 = q0 > 0.f ? q0 : 0.2f * q0;
      q1 = q1 > 0.f ? q1 : 0.2f * q1;
      q2 = q2 > 0.f ? q2 : 0.2f * q2;
      q3 = q3 > 0.f ? q3 : 0.2f * q3;
      ap += q0 * at4.x + q1 * at4.y + q2 * at4.z + q3 * at4.w;
    }
    p[fn] = ap;
  }
#pragma unroll
  for (int fn = 0; fn < 4; ++fn) {
    p[fn] += __shfl_xor(p[fn], 16);
    p[fn] += __shfl_xor(p[fn], 32);
  }
  if (lane < 16) {
    const int h = wave >> 1;
    const int g = wave & 1;
#pragma unroll
    for (int fn = 0; fn < 4; ++fn)
      red[h][g][fn * 16 + lane] = p[fn];
  }
  __syncthreads();
  if (tid < 128) {
    const int slot = tid & 63, h = tid >> 6;
    const int i = bm + slot;
    if (i < E) payload_f[2 * (size_t)i + h] = red[h][0][slot] + red[h][1][slot];
  }
}

// ---------------- per-node segment softmax + aggregation ----------------
// one wave per node; lanes 0-31 even CSR slots, 32-63 odd; within a 32-group
// lanes 0-15 = head0 weights, 16-31 = head1. Degree loop batched 8-deep.
__global__ __launch_bounds__(256) void aggregate_k(
    const ushort* __restrict__ xlr, const float2* __restrict__ payload,
    const int* __restrict__ rowptr, const int* __restrict__ srcs,
    const float* __restrict__ bias, ushort* __restrict__ hb,
    float* __restrict__ hf, int N, int relu) {
  const int n = blockIdx.x * 4 + (threadIdx.x >> 6);
  if (n >= N) return;
  const int lane = threadIdx.x & 63;
  const int half = lane >> 5;
  const int sl = lane & 31;
  const int hsel = sl >> 4;
  const int beg = rowptr[n], end = rowptr[n + 1];
  if (beg >= end) {
    if (lane < 16) {
      const int c0 = sl * 8;
      u16x8 ob;
      float o[8];
#pragma unroll
      for (int t = 0; t < 8; ++t) {
        float v = bias[c0 + t];
        if (relu) v = fmaxf(v, 0.f);
        o[t] = v;
        ob[t] = f2b(v);
      }
      *(u16x8*)(hb + (size_t)n * 128 + c0) = ob;
      if (hf) {
        *(float4*)(hf + (size_t)n * 128 + c0) = make_float4(o[0], o[1], o[2], o[3]);
        *(float4*)(hf + (size_t)n * 128 + c0 + 4) = make_float4(o[4], o[5], o[6], o[7]);
      }
    }
    return;
  }

  float m0 = -1e30f, m1 = -1e30f;
  for (int i = beg + half; i < end; i += 2) {
    const float2 lg = payload[i];
    m0 = fmaxf(m0, lg.x);
    m1 = fmaxf(m1, lg.y);
  }
  m0 = fmaxf(m0, __shfl_xor(m0, 32));
  m1 = fmaxf(m1, __shfl_xor(m1, 32));

  float s0 = 0.f, s1 = 0.f;
  float acc[8] = {};
  for (int base = beg + half; base < end; base += 16) {
    float2 lg[8];
    int sidx[8];
#pragma unroll
    for (int k = 0; k < 8; ++k) {
      const int i = min(base + 2 * k, end - 1);
      lg[k] = payload[i];
      sidx[k] = srcs[i];
    }
    u16x8 v[8];
#pragma unroll
    for (int k = 0; k < 8; ++k)
      v[k] = *(const u16x8*)(xlr + (((size_t)sidx[k]) << 9) + sl * 8);
    float wv[8];
#pragma unroll
    for (int k = 0; k < 8; ++k) {
      const bool ok = (base + 2 * k) < end;
      const float w0 = ok ? __expf(lg[k].x - m0) : 0.f;
      const float w1 = ok ? __expf(lg[k].y - m1) : 0.f;
      s0 += w0; s1 += w1;
      wv[k] = hsel ? w1 : w0;
    }
#pragma unroll
    for (int k = 0; k < 8; ++k)
#pragma unroll
      for (int t = 0; t < 8; ++t) acc[t] += wv[k] * b2f((ushort)v[k][t]);
  }
  s0 += __shfl_xor(s0, 32);
  s1 += __shfl_xor(s1, 32);
#pragma unroll
  for (int t = 0; t < 8; ++t) acc[t] += __shfl_xor(acc[t], 32);

  const float i0 = 1.f / (s0 + 1e-16f);
  const float i1 = 1.f / (s1 + 1e-16f);
  const float myinv = hsel ? i1 : i0;
  const int c0 = (sl & 15) * 8;
  float o[8];
#pragma unroll
  for (int t = 0; t < 8; ++t) {
    const float mine = acc[t] * myinv;
    const float other = __shfl_xor(mine, 16);
    float v = 0.5f * (mine + other) + bias[c0 + t];
    if (relu) v = fmaxf(v, 0.f);
    o[t] = v;
  }
  if (lane < 16) {
    u16x8 ob;
#pragma unroll
    for (int t = 0; t < 8; ++t) ob[t] = f2b(o[t]);
    *(u16x8*)(hb + (size_t)n * 128 + c0) = ob;
    if (hf) {
      *(float4*)(hf + (size_t)n * 128 + c0) = make_float4(o[0], o[1], o[2], o[3]);
      *(float4*)(hf + (size_t)n * 128 + c0 + 4) = make_float4(o[4], o[5], o[6], o[7]);
    }
  }
}

__global__ __launch_bounds__(128) void gather_k(const float* __restrict__ h,
                                                const int* __restrict__ master,
                                                float* __restrict__ out) {
  out[(size_t)blockIdx.x * 128 + threadIdx.x] =
      h[(size_t)master[blockIdx.x] * 128 + threadIdx.x];
}

// ---------------------------------------------------------------------------
extern "C" void kernel_launch(void* const* d_in, const int* in_sizes, int n_in,
                              void* d_out, int out_size, void* d_ws, size_t ws_size,
                              hipStream_t stream) {
  const float* x     = (const float*)d_in[0];
  const int*   ei    = (const int*)d_in[1];
  const float* eattr = (const float*)d_in[2];
  const int*   batch = (const int*)d_in[3];

  const int N  = in_sizes[3];
  const int E  = in_sizes[1] / 2;
  const int IN = in_sizes[0] / N;
  const int B  = out_size / 128;

  const int* src  = ei;
  const int* dstp = ei + E;

  char* p = (char*)d_ws;
  auto carve = [&](size_t bytes) {
    void* r = (void*)p;
    p += (bytes + 255) & ~(size_t)255;
    return r;
  };
  ushort* xb     = (ushort*)carve((size_t)N * 512 * 2);  // bf16(x); dead after L1 GEMM
  ushort* ebc    = (ushort*)carve((size_t)E * 64 * 2);   // bf16 edge_attr, CSR order
  ushort* xlr    = (ushort*)carve((size_t)N * 512 * 2);  // [xl | xr] bf16
  ushort* h1b    = (ushort*)carve((size_t)N * 128 * 2);
  ushort* h2b    = (ushort*)carve((size_t)N * 128 * 2);
  ushort* wt0    = (ushort*)carve((size_t)512 * 512 * 2);
  ushort* wt1    = (ushort*)carve((size_t)512 * 128 * 2);
  ushort* wt2    = (ushort*)carve((size_t)512 * 128 * 2);
  ushort* wet    = (ushort*)carve((size_t)3 * 256 * 64 * 2);
  float2* payload= (float2*)carve((size_t)E * 8);        // CSR-ordered logits
  int* counts    = (int*)carve(((size_t)N + B) * 4);
  int* master    = counts + N;
  int* rowptr    = (int*)carve(((size_t)N + 1) * 4);
  int* cursor    = (int*)carve((size_t)N * 4);
  int* csr       = (int*)carve((size_t)E * 4);
  int* srcs      = (int*)carve((size_t)E * 4);           // src in CSR order
  int* dsts      = (int*)carve((size_t)E * 4);           // dst in CSR order
  int* bsum      = (int*)carve(256 * 4);
  float* hf      = (float*)xb;                            // f32 h3 aliases dead xb
  (void)ws_size; (void)n_in;

  const int G = (N + SCAN_CHUNK - 1) / SCAN_CHUNK;

  // setup (once; reused by all 3 layers)
  hipMemsetAsync(counts, 0, ((size_t)N + B) * 4, stream);
  hist_k<<<(E + 255) / 256, 256, 0, stream>>>(dstp, counts, E);
  scan_sum_k<<<G, 256, 0, stream>>>(counts, bsum, N);
  scan_bsum_k<<<1, 256, 0, stream>>>(bsum, G);
  scan_out_k<<<G, 256, 0, stream>>>(counts, bsum, rowptr, cursor, N, E);
  scatter_k<<<(E + 255) / 256, 256, 0, stream>>>(dstp, src, cursor, csr, srcs,
                                                 dsts, E);
  master_k<<<(N + 255) / 256, 256, 0, stream>>>(batch, master, N);
  ebp_cvt_k<<<(E * 16 + 255) / 256, 256, 0, stream>>>(eattr, csr, ebc, E);

  {
    int n4 = N * IN / 4;
    cvt_k<<<(n4 + 255) / 256, 256, 0, stream>>>(x, xb, n4);
  }

  wtall_k<<<dim3((512 * IN + 255) / 256, 4), 256, 0, stream>>>(
      (const float*)d_in[4], (const float*)d_in[5], (const float*)d_in[6],
      (const float*)d_in[9], (const float*)d_in[10], (const float*)d_in[11],
      (const float*)d_in[14], (const float*)d_in[15], (const float*)d_in[16],
      wt0, wt1, wt2, wet, IN);

  const int edge_grid = (E + 63) / 64;
  const int agg_grid = (N + 3) / 4;
  ushort* wts[3] = {wt0, wt1, wt2};
  for (int l = 0; l < 3; ++l) {
    const float* att = (const float*)d_in[4 + 5 * l + 3];
    const float* bv  = (const float*)d_in[4 + 5 * l + 4];
    const int K = (l == 0) ? IN : 128;

    const ushort* Ab = (l == 0) ? xb : ((l == 1) ? h1b : h2b);
    gemm_bf16<<<dim3((N + 127) / 128, 2), 512, 0, stream>>>(Ab, wts[l], xlr,
                                                            N, 512, K);

    edge_fused_k<<<edge_grid, 256, 0, stream>>>(ebc, wet + (size_t)l * 16384,
                                                xlr, att, srcs, dsts,
                                                (float*)payload, E);

    ushort* hb = (l == 0) ? h1b : ((l == 1) ? h2b : h1b);
    aggregate_k<<<agg_grid, 256, 0, stream>>>(xlr, payload, rowptr, srcs, bv,
                                              hb, (l == 2) ? hf : nullptr, N,
                                              l < 2 ? 1 : 0);
  }

  gather_k<<<B, 128, 0, stream>>>(hf, master, (float*)d_out);
}

// Round 14
// 594.437 us; speedup vs baseline: 1.9743x; 1.1025x over previous
//
#include <hip/hip_runtime.h>
#include <cstdint>
#include <cstddef>

// ---------------------------------------------------------------------------
// GATv2 x3 + master pooling, bf16-MFMA, CSR-ordered edge pipeline.
// Round-11 configuration (best known: 596us) + bf16-only final h (no f32
// mirror; gather_k converts the 64 master rows).
// ---------------------------------------------------------------------------

typedef __attribute__((ext_vector_type(8))) short bf16x8;
typedef __attribute__((ext_vector_type(4))) float f32x4;
typedef __attribute__((ext_vector_type(8))) unsigned short u16x8;

static __device__ __forceinline__ ushort f2b(float f) {
  uint32_t u = __float_as_uint(f);
  uint32_t r = (u + 0x7fffu + ((u >> 16) & 1u)) >> 16;  // RNE
  return (ushort)r;
}
static __device__ __forceinline__ float b2f(ushort b) {
  return __uint_as_float(((uint32_t)b) << 16);
}

#define GLOAD_LDS16(gp, lp)                                        \
  __builtin_amdgcn_global_load_lds(                                \
      (const __attribute__((address_space(1))) void*)(gp),         \
      (__attribute__((address_space(3))) void*)(lp), 16, 0, 0)

// ---------------- CSR build ----------------
__global__ __launch_bounds__(256) void hist_k(const int* __restrict__ dst,
                                              int* __restrict__ counts, int E) {
  int e = blockIdx.x * 256 + threadIdx.x;
  if (e < E) atomicAdd(&counts[dst[e]], 1);
}

#define SCAN_CHUNK 1024
__global__ __launch_bounds__(256) void scan_sum_k(const int* __restrict__ counts,
                                                  int* __restrict__ bsum, int N) {
  __shared__ int ws[4];
  const int t = threadIdx.x;
  const int i0 = blockIdx.x * SCAN_CHUNK + t * 4;
  int s = 0;
  if (i0 + 3 < N) {
    int4 v = *(const int4*)(counts + i0);
    s = v.x + v.y + v.z + v.w;
  } else {
    for (int k = 0; k < 4; ++k)
      if (i0 + k < N) s += counts[i0 + k];
  }
  for (int off = 1; off < 64; off <<= 1) s += __shfl_xor(s, off);
  if ((t & 63) == 0) ws[t >> 6] = s;
  __syncthreads();
  if (t == 0) bsum[blockIdx.x] = ws[0] + ws[1] + ws[2] + ws[3];
}

__global__ __launch_bounds__(256) void scan_bsum_k(int* __restrict__ bsum, int G) {
  __shared__ int tmp[256];
  const int t = threadIdx.x;
  const int v = (t < G) ? bsum[t] : 0;
  tmp[t] = v;
  __syncthreads();
  for (int off = 1; off < 256; off <<= 1) {
    int u = (t >= off) ? tmp[t - off] : 0;
    __syncthreads();
    tmp[t] += u;
    __syncthreads();
  }
  if (t < G) bsum[t] = tmp[t] - v;  // exclusive
}

__global__ __launch_bounds__(256) void scan_out_k(const int* __restrict__ counts,
                                                  const int* __restrict__ bsum,
                                                  int* __restrict__ rowptr,
                                                  int* __restrict__ cursor,
                                                  int N, int E) {
  __shared__ int wsum[4];
  const int t = threadIdx.x;
  const int lane = t & 63, w = t >> 6;
  const int i0 = blockIdx.x * SCAN_CHUNK + t * 4;
  int v[4] = {0, 0, 0, 0};
  if (i0 + 3 < N) {
    int4 q = *(const int4*)(counts + i0);
    v[0] = q.x; v[1] = q.y; v[2] = q.z; v[3] = q.w;
  } else {
    for (int k = 0; k < 4; ++k)
      if (i0 + k < N) v[k] = counts[i0 + k];
  }
  const int s = v[0] + v[1] + v[2] + v[3];
  int inc = s;
  for (int off = 1; off < 64; off <<= 1) {
    int u = __shfl_up(inc, off);
    if (lane >= off) inc += u;
  }
  if (lane == 63) wsum[w] = inc;
  __syncthreads();
  int wpre = 0;
  for (int k = 0; k < w; ++k) wpre += wsum[k];
  int run = bsum[blockIdx.x] + wpre + inc - s;  // exclusive prefix
  for (int k = 0; k < 4; ++k) {
    const int i = i0 + k;
    if (i < N) {
      rowptr[i] = run;
      cursor[i] = run;
      run += v[k];
    }
  }
  if (blockIdx.x == 0 && t == 0) rowptr[N] = E;
}

// csr[p]=e, srcs[p]=src[e], dsts[p]=dst[e]
__global__ __launch_bounds__(256) void scatter_k(const int* __restrict__ dst,
                                                 const int* __restrict__ src,
                                                 int* __restrict__ cursor,
                                                 int* __restrict__ csr,
                                                 int* __restrict__ srcs,
                                                 int* __restrict__ dsts, int E) {
  int e = blockIdx.x * 256 + threadIdx.x;
  if (e < E) {
    int p = atomicAdd(&cursor[dst[e]], 1);
    csr[p] = e;
    srcs[p] = src[e];
    dsts[p] = dst[e];
  }
}

__global__ __launch_bounds__(256) void master_k(const int* __restrict__ batch,
                                                int* __restrict__ master, int N) {
  int i = blockIdx.x * 256 + threadIdx.x;
  if (i < N) {
    int b = batch[i];
    if (i == N - 1 || batch[i + 1] != b) master[b] = i;
  }
}

// ---------------- conversions ----------------
__global__ __launch_bounds__(256) void cvt_k(const float* __restrict__ in,
                                             ushort* __restrict__ out, int n4) {
  int i = blockIdx.x * 256 + threadIdx.x;
  if (i < n4) {
    float4 v = ((const float4*)in)[i];
    ushort4 o;
    o.x = f2b(v.x); o.y = f2b(v.y); o.z = f2b(v.z); o.w = f2b(v.w);
    ((ushort4*)out)[i] = o;
  }
}

__global__ __launch_bounds__(256) void ebp_cvt_k(const float* __restrict__ ea,
                                                 const int* __restrict__ csr,
                                                 ushort* __restrict__ ebc, int E) {
  const int idx = blockIdx.x * 256 + threadIdx.x;
  const int i = idx >> 4, t = idx & 15;
  if (i < E) {
    float4 v = *(const float4*)(ea + (size_t)csr[i] * 64 + t * 4);
    ushort4 o;
    o.x = f2b(v.x); o.y = f2b(v.y); o.z = f2b(v.z); o.w = f2b(v.w);
    *(ushort4*)(ebc + (size_t)i * 64 + t * 4) = o;
  }
}

// all weight transposes (3 layers) in one launch
__global__ __launch_bounds__(256) void wtall_k(
    const float* __restrict__ w1l, const float* __restrict__ w1r,
    const float* __restrict__ w1e, const float* __restrict__ w2l,
    const float* __restrict__ w2r, const float* __restrict__ w2e,
    const float* __restrict__ w3l, const float* __restrict__ w3r,
    const float* __restrict__ w3e, ushort* __restrict__ wt0,
    ushort* __restrict__ wt1, ushort* __restrict__ wt2,
    ushort* __restrict__ wet, int IN) {
  const int y = blockIdx.y;
  const int i = blockIdx.x * 256 + threadIdx.x;
  if (y < 3) {
    const int K = (y == 0) ? IN : 128;
    ushort* out = (y == 0) ? wt0 : ((y == 1) ? wt1 : wt2);
    const float* Wl = (y == 0) ? w1l : ((y == 1) ? w2l : w3l);
    const float* Wr = (y == 0) ? w1r : ((y == 1) ? w2r : w3r);
    if (i < 512 * K) {
      const int n = i / K, k = i - n * K;
      const float* W = (n < 256) ? Wl : Wr;
      out[(size_t)n * K + k] = f2b(W[(size_t)k * 256 + (n & 255)]);
    }
  } else {
    if (i < 3 * 256 * 64) {
      const int l = i / (256 * 64);
      const int r = i - l * 256 * 64;
      const int n = r / 64, k = r - n * 64;
      const float* W = (l == 0) ? w1e : ((l == 1) ? w2e : w3e);
      wet[(size_t)l * 16384 + (size_t)n * 64 + k] = f2b(W[(size_t)k * 256 + n]);
    }
  }
}

// ---------------- bf16 MFMA GEMM (node features) ----------------
// C[M,512] = A[M,K] @ Bt[512,K]^T. 128x256 tile, BK=64, 8 waves (2x4).
__global__ __launch_bounds__(512) void gemm_bf16(const ushort* __restrict__ A,
                                                 const ushort* __restrict__ Bt,
                                                 ushort* __restrict__ C,
                                                 int M, int N, int K) {
  __shared__ ushort As[128 * 64];  // 16KB
  __shared__ ushort Bs[256 * 64];  // 32KB
  const int tid = threadIdx.x;
  const int lane = tid & 63;
  const int wave = tid >> 6;        // 0..7
  const int bm = blockIdx.x * 128;
  const int bn = blockIdx.y * 256;
  const int wm = (wave >> 2) * 64;  // 0,64
  const int wn = (wave & 3) * 64;   // 0..192
  const int l15 = lane & 15;
  const int t_hi = lane >> 4;

  f32x4 acc[4][4] = {};

  const int wb = tid & ~63;  // wave-uniform base within 512
  int arow[2], aks[2];
#pragma unroll
  for (int i = 0; i < 2; ++i) {
    const int j = i * 512 + wb + lane;
    arow[i] = j >> 3;                     // 0..127
    aks[i] = (j & 7) ^ (arow[i] & 7);
  }
  int brow[4], bks[4];
#pragma unroll
  for (int i = 0; i < 4; ++i) {
    const int j = i * 512 + wb + lane;
    brow[i] = j >> 3;                     // 0..255
    bks[i] = (j & 7) ^ (brow[i] & 7);
  }

  for (int k0 = 0; k0 < K; k0 += 64) {
#pragma unroll
    for (int i = 0; i < 2; ++i) {
      const int ar = min(bm + arow[i], M - 1);  // clamp tail (masked on store)
      GLOAD_LDS16(A + (size_t)ar * K + k0 + aks[i] * 8,
                  As + (size_t)(i * 512 + wb) * 8);
    }
#pragma unroll
    for (int i = 0; i < 4; ++i) {
      GLOAD_LDS16(Bt + (size_t)(bn + brow[i]) * K + k0 + bks[i] * 8,
                  Bs + (size_t)(i * 512 + wb) * 8);
    }
    __syncthreads();
#pragma unroll
    for (int ks = 0; ks < 2; ++ks) {
      bf16x8 af[4], bfr[4];
#pragma unroll
      for (int f = 0; f < 4; ++f) {
        const int q = (ks * 4 + t_hi) ^ (lane & 7);
        af[f]  = *(const bf16x8*)&As[(wm + f * 16 + l15) * 64 + q * 8];
        bfr[f] = *(const bf16x8*)&Bs[(wn + f * 16 + l15) * 64 + q * 8];
      }
#pragma unroll
      for (int fm = 0; fm < 4; ++fm)
#pragma unroll
        for (int fn = 0; fn < 4; ++fn)
          acc[fm][fn] = __builtin_amdgcn_mfma_f32_16x16x32_bf16(
              af[fm], bfr[fn], acc[fm][fn], 0, 0, 0);
    }
    __syncthreads();
  }
#pragma unroll
  for (int fm = 0; fm < 4; ++fm) {
    const int r0 = bm + wm + fm * 16 + t_hi * 4;
#pragma unroll
    for (int j = 0; j < 4; ++j) {
      const int gr = r0 + j;
      if (gr < M) {
#pragma unroll
        for (int fn = 0; fn < 4; ++fn) {
          const int gc = bn + wn + fn * 16 + l15;
          C[(size_t)gr * N + gc] = f2b(acc[fm][fn][j]);
        }
      }
    }
  }
}

// ---------------- fused edge projection + logits (CSR order) ----------------
// grid ceil(E/64), 256 threads (4 waves), 64 edges per block. Wave w covers
// c-slice wm = w*64 over all 64 slots (round-11 proven version).
__global__ __launch_bounds__(256) void edge_fused_k(
    const ushort* __restrict__ ebc,  // [E][64] CSR-ordered
    const ushort* __restrict__ wet,  // [256][64] (this layer)
    const ushort* __restrict__ xlr,  // [N][512]
    const float* __restrict__ att,   // [256]
    const int* __restrict__ srcs, const int* __restrict__ dsts,
    float* __restrict__ payload_f, int E) {
  __shared__ ushort Bs[64 * 64];      // 8KB
  __shared__ int sSrc[64], sDst[64];
  __shared__ float red[2][2][64];     // [head][c-group][slot]

  const int tid = threadIdx.x;
  const int lane = tid & 63;
  const int wave = tid >> 6;           // 0..3
  const int bm = blockIdx.x * 64;      // CSR slot base
  const int wm = wave * 64;            // c offset 0..255
  const int l15 = lane & 15;
  const int t_hi = lane >> 4;

  if (tid < 64) {
    const int i = min(bm + tid, E - 1);
    sSrc[tid] = srcs[i];
    sDst[tid] = dsts[i];
  }

  // stage ebc tile (64 rows x K=64): swizzle-on-source, linear LDS dest
  const int wb = tid & ~63;
#pragma unroll
  for (int i = 0; i < 2; ++i) {
    const int j = i * 256 + wb + lane;
    const int jrow = j >> 3;
    const int jks = (j & 7) ^ (jrow & 7);
    const int er = min(bm + jrow, E - 1);
    GLOAD_LDS16(ebc + (size_t)er * 64 + jks * 8,
                Bs + (size_t)(i * 256 + wb) * 8);
  }
  __syncthreads();

  f32x4 acc[4][4] = {};
#pragma unroll
  for (int ks = 0; ks < 2; ++ks) {
    bf16x8 af[4], bfr[4];
#pragma unroll
    for (int f = 0; f < 4; ++f) {
      const int q = (ks * 4 + t_hi) ^ (lane & 7);
      bfr[f] = *(const bf16x8*)&Bs[(f * 16 + l15) * 64 + q * 8];
      af[f] = *(const bf16x8*)&wet[(size_t)(wm + f * 16 + l15) * 64 +
                                   (ks * 4 + t_hi) * 8];
    }
#pragma unroll
    for (int fm = 0; fm < 4; ++fm)
#pragma unroll
      for (int fn = 0; fn < 4; ++fn)
        acc[fm][fn] = __builtin_amdgcn_mfma_f32_16x16x32_bf16(
            af[fm], bfr[fn], acc[fm][fn], 0, 0, 0);
  }

  // epilogue: per lane, 4 slot-groups (fn), 16 c-values each (fm x j)
  float p[4];
#pragma unroll
  for (int fn = 0; fn < 4; ++fn) {
    const int el = fn * 16 + l15;
    const int s = sSrc[el];
    const int d = sDst[el];
    const ushort* xlp = xlr + (((size_t)s) << 9) + wm + t_hi * 4;
    const ushort* xrp = xlr + (((size_t)d) << 9) + 256 + wm + t_hi * 4;
    float ap = 0.f;
#pragma unroll
    for (int fm = 0; fm < 4; ++fm) {
      const ushort4 xa = *(const ushort4*)(xlp + fm * 16);
      const ushort4 xc = *(const ushort4*)(xrp + fm * 16);
      const float4 at4 = *(const float4*)(att + wm + fm * 16 + t_hi * 4);
      float q0 = acc[fm][fn][0] + b2f(xa.x) + b2f(xc.x);
      float q1 = acc[fm][fn][1] + b2f(xa.y) + b2f(xc.y);
      float q2 = acc[fm][fn][2] + b2f(xa.z) + b2f(xc.z);
      float q3 = acc[fm][fn][3] + b2f(xa.w) + b2f(xc.w);
      q0 = q0 > 0.f ? q0 : 0.2f * q0;
      q1 = q1 > 0.f ? q1 : 0.2f * q1;
      q2 = q2 > 0.f ? q2 : 0.2f * q2;
      q3 = q3 > 0.f ? q3 : 0.2f * q3;
      ap += q0 * at4.x + q1 * at4.y + q2 * at4.z + q3 * at4.w;
    }
    p[fn] = ap;
  }
#pragma unroll
  for (int fn = 0; fn < 4; ++fn) {
    p[fn] += __shfl_xor(p[fn], 16);
    p[fn] += __shfl_xor(p[fn], 32);
  }
  if (lane < 16) {
    const int h = wave >> 1;
    const int g = wave & 1;
#pragma unroll
    for (int fn = 0; fn < 4; ++fn)
      red[h][g][fn * 16 + lane] = p[fn];
  }
  __syncthreads();
  if (tid < 128) {
    const int slot = tid & 63, h = tid >> 6;
    const int i = bm + slot;
    if (i < E) payload_f[2 * (size_t)i + h] = red[h][0][slot] + red[h][1][slot];
  }
}

// ---------------- per-node segment softmax + aggregation ----------------
// one wave per node; lanes 0-31 even CSR slots, 32-63 odd; within a 32-group
// lanes 0-15 = head0 weights, 16-31 = head1. Degree loop batched 4-deep
// (matches the ~8 average degree; deeper batching wastes clamped gathers).
__global__ __launch_bounds__(256) void aggregate_k(
    const ushort* __restrict__ xlr, const float2* __restrict__ payload,
    const int* __restrict__ rowptr, const int* __restrict__ srcs,
    const float* __restrict__ bias, ushort* __restrict__ hb,
    int N, int relu) {
  const int n = blockIdx.x * 4 + (threadIdx.x >> 6);
  if (n >= N) return;
  const int lane = threadIdx.x & 63;
  const int half = lane >> 5;
  const int sl = lane & 31;
  const int hsel = sl >> 4;
  const int beg = rowptr[n], end = rowptr[n + 1];
  if (beg >= end) {
    if (lane < 16) {
      const int c0 = sl * 8;
      u16x8 ob;
#pragma unroll
      for (int t = 0; t < 8; ++t) {
        float v = bias[c0 + t];
        if (relu) v = fmaxf(v, 0.f);
        ob[t] = f2b(v);
      }
      *(u16x8*)(hb + (size_t)n * 128 + c0) = ob;
    }
    return;
  }

  float m0 = -1e30f, m1 = -1e30f;
  for (int i = beg + half; i < end; i += 2) {
    const float2 lg = payload[i];
    m0 = fmaxf(m0, lg.x);
    m1 = fmaxf(m1, lg.y);
  }
  m0 = fmaxf(m0, __shfl_xor(m0, 32));
  m1 = fmaxf(m1, __shfl_xor(m1, 32));

  float s0 = 0.f, s1 = 0.f;
  float acc[8] = {};
  for (int base = beg + half; base < end; base += 8) {
    float2 lg[4];
    int sidx[4];
#pragma unroll
    for (int k = 0; k < 4; ++k) {
      const int i = min(base + 2 * k, end - 1);
      lg[k] = payload[i];
      sidx[k] = srcs[i];
    }
    u16x8 v[4];
#pragma unroll
    for (int k = 0; k < 4; ++k)
      v[k] = *(const u16x8*)(xlr + (((size_t)sidx[k]) << 9) + sl * 8);
    float wv[4];
#pragma unroll
    for (int k = 0; k < 4; ++k) {
      const bool ok = (base + 2 * k) < end;
      const float w0 = ok ? __expf(lg[k].x - m0) : 0.f;
      const float w1 = ok ? __expf(lg[k].y - m1) : 0.f;
      s0 += w0; s1 += w1;
      wv[k] = hsel ? w1 : w0;
    }
#pragma unroll
    for (int k = 0; k < 4; ++k)
#pragma unroll
      for (int t = 0; t < 8; ++t) acc[t] += wv[k] * b2f((ushort)v[k][t]);
  }
  s0 += __shfl_xor(s0, 32);
  s1 += __shfl_xor(s1, 32);
#pragma unroll
  for (int t = 0; t < 8; ++t) acc[t] += __shfl_xor(acc[t], 32);

  const float i0 = 1.f / (s0 + 1e-16f);
  const float i1 = 1.f / (s1 + 1e-16f);
  const float myinv = hsel ? i1 : i0;
  const int c0 = (sl & 15) * 8;
  float o[8];
#pragma unroll
  for (int t = 0; t < 8; ++t) {
    const float mine = acc[t] * myinv;
    const float other = __shfl_xor(mine, 16);
    float v = 0.5f * (mine + other) + bias[c0 + t];
    if (relu) v = fmaxf(v, 0.f);
    o[t] = v;
  }
  if (lane < 16) {
    u16x8 ob;
#pragma unroll
    for (int t = 0; t < 8; ++t) ob[t] = f2b(o[t]);
    *(u16x8*)(hb + (size_t)n * 128 + c0) = ob;
  }
}

// final pooling: read bf16 h rows of the 64 masters, emit f32
__global__ __launch_bounds__(128) void gather_k(const ushort* __restrict__ h,
                                                const int* __restrict__ master,
                                                float* __restrict__ out) {
  out[(size_t)blockIdx.x * 128 + threadIdx.x] =
      b2f(h[(size_t)master[blockIdx.x] * 128 + threadIdx.x]);
}

// ---------------------------------------------------------------------------
extern "C" void kernel_launch(void* const* d_in, const int* in_sizes, int n_in,
                              void* d_out, int out_size, void* d_ws, size_t ws_size,
                              hipStream_t stream) {
  const float* x     = (const float*)d_in[0];
  const int*   ei    = (const int*)d_in[1];
  const float* eattr = (const float*)d_in[2];
  const int*   batch = (const int*)d_in[3];

  const int N  = in_sizes[3];
  const int E  = in_sizes[1] / 2;
  const int IN = in_sizes[0] / N;
  const int B  = out_size / 128;

  const int* src  = ei;
  const int* dstp = ei + E;

  char* p = (char*)d_ws;
  auto carve = [&](size_t bytes) {
    void* r = (void*)p;
    p += (bytes + 255) & ~(size_t)255;
    return r;
  };
  ushort* xb     = (ushort*)carve((size_t)N * 512 * 2);  // bf16(x); dead after L1 GEMM
  ushort* ebc    = (ushort*)carve((size_t)E * 64 * 2);   // bf16 edge_attr, CSR order
  ushort* xlr    = (ushort*)carve((size_t)N * 512 * 2);  // [xl | xr] bf16
  ushort* h1b    = (ushort*)carve((size_t)N * 128 * 2);
  ushort* h2b    = (ushort*)carve((size_t)N * 128 * 2);
  ushort* wt0    = (ushort*)carve((size_t)512 * 512 * 2);
  ushort* wt1    = (ushort*)carve((size_t)512 * 128 * 2);
  ushort* wt2    = (ushort*)carve((size_t)512 * 128 * 2);
  ushort* wet    = (ushort*)carve((size_t)3 * 256 * 64 * 2);
  float2* payload= (float2*)carve((size_t)E * 8);        // CSR-ordered logits
  int* counts    = (int*)carve(((size_t)N + B) * 4);
  int* master    = counts + N;
  int* rowptr    = (int*)carve(((size_t)N + 1) * 4);
  int* cursor    = (int*)carve((size_t)N * 4);
  int* csr       = (int*)carve((size_t)E * 4);
  int* srcs      = (int*)carve((size_t)E * 4);           // src in CSR order
  int* dsts      = (int*)carve((size_t)E * 4);           // dst in CSR order
  int* bsum      = (int*)carve(256 * 4);
  (void)ws_size; (void)n_in;

  const int G = (N + SCAN_CHUNK - 1) / SCAN_CHUNK;

  // setup (once; reused by all 3 layers)
  hipMemsetAsync(counts, 0, ((size_t)N + B) * 4, stream);
  hist_k<<<(E + 255) / 256, 256, 0, stream>>>(dstp, counts, E);
  scan_sum_k<<<G, 256, 0, stream>>>(counts, bsum, N);
  scan_bsum_k<<<1, 256, 0, stream>>>(bsum, G);
  scan_out_k<<<G, 256, 0, stream>>>(counts, bsum, rowptr, cursor, N, E);
  scatter_k<<<(E + 255) / 256, 256, 0, stream>>>(dstp, src, cursor, csr, srcs,
                                                 dsts, E);
  master_k<<<(N + 255) / 256, 256, 0, stream>>>(batch, master, N);
  ebp_cvt_k<<<(E * 16 + 255) / 256, 256, 0, stream>>>(eattr, csr, ebc, E);

  {
    int n4 = N * IN / 4;
    cvt_k<<<(n4 + 255) / 256, 256, 0, stream>>>(x, xb, n4);
  }

  wtall_k<<<dim3((512 * IN + 255) / 256, 4), 256, 0, stream>>>(
      (const float*)d_in[4], (const float*)d_in[5], (const float*)d_in[6],
      (const float*)d_in[9], (const float*)d_in[10], (const float*)d_in[11],
      (const float*)d_in[14], (const float*)d_in[15], (const float*)d_in[16],
      wt0, wt1, wt2, wet, IN);

  const int edge_grid = (E + 63) / 64;
  const int agg_grid = (N + 3) / 4;
  ushort* wts[3] = {wt0, wt1, wt2};
  for (int l = 0; l < 3; ++l) {
    const float* att = (const float*)d_in[4 + 5 * l + 3];
    const float* bv  = (const float*)d_in[4 + 5 * l + 4];
    const int K = (l == 0) ? IN : 128;

    const ushort* Ab = (l == 0) ? xb : ((l == 1) ? h1b : h2b);
    gemm_bf16<<<dim3((N + 127) / 128, 2), 512, 0, stream>>>(Ab, wts[l], xlr,
                                                            N, 512, K);

    edge_fused_k<<<edge_grid, 256, 0, stream>>>(ebc, wet + (size_t)l * 16384,
                                                xlr, att, srcs, dsts,
                                                (float*)payload, E);

    ushort* hb = (l == 0) ? h1b : ((l == 1) ? h2b : h1b);
    aggregate_k<<<agg_grid, 256, 0, stream>>>(xlr, payload, rowptr, srcs, bv,
                                              hb, N, l < 2 ? 1 : 0);
  }

  gather_k<<<B, 128, 0, stream>>>(h1b, master, (float*)d_out);
}